// Round 1
// baseline (672.425 us; speedup 1.0000x reference)
//
#include <hip/hip_runtime.h>

// Problem constants
#define N_    8
#define TP_   2048
#define E_    4096
#define S_    8
#define C_    64
#define T_    16384      // TP_*S_
#define TS_   131072     // T_*S_
#define OUTW  17         // V+1
#define OUT_ELEMS 17825792  // N_*TS_*OUTW

typedef __attribute__((ext_vector_type(8))) short short8;
typedef __attribute__((ext_vector_type(4))) float float4v;

static __device__ __forceinline__ unsigned short f2bf(float f) {
    unsigned int u = __builtin_bit_cast(unsigned int, f);
    u += 0x7FFFu + ((u >> 16) & 1u);   // round-to-nearest-even
    return (unsigned short)(u >> 16);
}

// ---------------------------------------------------------------------------
// prep: Bb[(s*64+c)*4096 + e] = bf16(W1[e,c,s]); K2[s2] = b2 + sum_c b1[c]*W2[c,0,s2]
// ---------------------------------------------------------------------------
__global__ __launch_bounds__(256) void prep_kernel(
    const float* __restrict__ W1, const float* __restrict__ b1,
    const float* __restrict__ W2, const float* __restrict__ b2,
    unsigned short* __restrict__ Bb, float* __restrict__ K2)
{
    if (blockIdx.x == 0 && threadIdx.x < 8) {
        int s2 = threadIdx.x;
        float acc = b2[0];
        for (int c = 0; c < C_; ++c) acc += b1[c] * W2[c * S_ + s2];
        K2[s2] = acc;
    }
    size_t i = (size_t)blockIdx.x * 256 + threadIdx.x;   // over 4096*512 = 2097152
    if (i < (size_t)E_ * C_ * S_) {
        int e   = (int)(i & (E_ - 1));
        int row = (int)(i >> 12);          // s*64 + c
        int s   = row >> 6;
        int c   = row & 63;
        Bb[i] = f2bf(W1[(size_t)e * (C_ * S_) + c * S_ + s]);
    }
}

// ---------------------------------------------------------------------------
// compact: per (n,s) block builds the gathered row list.
//   selected(t) = (t < idx_n) && (value[n,t]==2);  idx_n = first argmax of sorted depth
//   sel_tp[g][k] = t>>3 (which x row), sel_j[g][k] = global rank j (output row)
// ---------------------------------------------------------------------------
__global__ __launch_bounds__(1024) void compact_kernel(
    const int* __restrict__ value, const int* __restrict__ depth,
    int* __restrict__ cnt_ns, int* __restrict__ sel_tp, int* __restrict__ sel_j)
{
    int g = blockIdx.x;          // n*8 + s
    int n = g >> 3;
    int s = g & 7;
    int tid = threadIdx.x;

    __shared__ int idx_sh;
    __shared__ unsigned int sc[1024];

    if (tid == 0) {
        const int* d = depth + (size_t)n * T_;
        int maxv = d[T_ - 1];
        int lo = 0, hi = T_ - 1;
        while (lo < hi) {            // first occurrence of max (depth sorted asc)
            int mid = (lo + hi) >> 1;
            if (d[mid] == maxv) hi = mid; else lo = mid + 1;
        }
        idx_sh = lo;
    }
    __syncthreads();
    int idx = idx_sh;
    const int* val = value + (size_t)n * T_;

    int t0 = tid * 16;
    unsigned int packed = 0;     // (global count << 16) | s-residue count
    for (int i = 0; i < 16; ++i) {
        int t = t0 + i;
        if (t < idx && val[t] == 2) {
            packed += 0x10000u;
            if ((t & 7) == s) packed += 1u;
        }
    }
    sc[tid] = packed;
    __syncthreads();
    for (int off = 1; off < 1024; off <<= 1) {   // Hillis-Steele inclusive scan
        unsigned int v = (tid >= off) ? sc[tid - off] : 0u;
        __syncthreads();
        sc[tid] += v;
        __syncthreads();
    }
    unsigned int excl = sc[tid] - packed;
    int any_rank = (int)(excl >> 16);
    int s_rank   = (int)(excl & 0xFFFFu);
    for (int i = 0; i < 16; ++i) {
        int t = t0 + i;
        if (t < idx && val[t] == 2) {
            if ((t & 7) == s) {
                sel_tp[g * 2048 + s_rank] = t >> 3;
                sel_j [g * 2048 + s_rank] = any_rank;
                ++s_rank;
            }
            ++any_rank;
        }
    }
    if (tid == 1023) cnt_ns[g] = (int)(sc[1023] & 0xFFFFu);
}

// ---------------------------------------------------------------------------
// fill: out[i] = b2 * W3[i % 17]   (the y==0 tail; selected rows overwritten later)
// ---------------------------------------------------------------------------
__global__ __launch_bounds__(256) void fill_kernel(
    float* __restrict__ out, const float* __restrict__ W3, const float* __restrict__ b2)
{
    size_t i = (size_t)blockIdx.x * 256 + threadIdx.x;
    if (i < (size_t)OUT_ELEMS) out[i] = b2[0] * W3[i % OUTW];
}

// ---------------------------------------------------------------------------
// main: gathered bf16 MFMA GEMM (64 rows x 64 ch, K=4096) + fused conv2/linear
// grid = (32 tiles, 64 groups); block = 256
// ---------------------------------------------------------------------------
__global__ __launch_bounds__(256) void main_kernel(
    const float* __restrict__ x, const unsigned short* __restrict__ Bb,
    const int* __restrict__ cnt_ns, const int* __restrict__ sel_tp,
    const int* __restrict__ sel_j, const float* __restrict__ K2,
    const float* __restrict__ W2, const float* __restrict__ W3,
    float* __restrict__ out)
{
    int g = blockIdx.y;
    int n = g >> 3;
    int s = g & 7;
    int cnt = cnt_ns[g];
    int m0 = blockIdx.x * 64;
    if (m0 >= cnt) return;
    int rows = min(64, cnt - m0);

    __shared__ unsigned short As[64][72];   // [row][k] bf16, +8 pad
    __shared__ unsigned short Bs[64][72];   // [c][k]  bf16 (B^T), +8 pad
    __shared__ float Cl[64][68];            // fp32 C tile for epilogue
    __shared__ int tp_l[64];
    __shared__ int j_l[64];
    __shared__ float W2s[C_ * S_];
    __shared__ float W3s[OUTW];
    __shared__ float K2s[S_];

    const int tid = threadIdx.x;
    if (tid < 64) {
        int tp = 0, j = 0;
        if (tid < rows) {
            tp = sel_tp[g * 2048 + m0 + tid];
            j  = sel_j [g * 2048 + m0 + tid];
        }
        tp_l[tid] = tp;
        j_l[tid]  = j;
    }
    for (int i = tid; i < C_ * S_; i += 256) W2s[i] = W2[i];
    if (tid < OUTW) W3s[tid] = W3[tid];
    if (tid < S_)   K2s[tid] = K2[tid];
    __syncthreads();

    // staging assignment: thread covers rows r+16l, k-span [kq, kq+4)
    const int r  = tid >> 4;          // 0..15
    const int kq = (tid & 15) << 2;   // 0..60
    const float* aptr[4];
    const unsigned short* bptr[4];
#pragma unroll
    for (int l = 0; l < 4; ++l) {
        int row = r + (l << 4);
        aptr[l] = x + ((size_t)n * TP_ + tp_l[row]) * E_ + kq;
        bptr[l] = Bb + ((size_t)(s * C_) + row) * E_ + kq;
    }

    const int lane = tid & 63;
    const int w    = tid >> 6;        // wave id: rows [w*16, w*16+16)
    const int m    = lane & 15;
    const int q    = lane >> 4;

    float4v acc[4];
#pragma unroll
    for (int nt = 0; nt < 4; ++nt) acc[nt] = (float4v){0.f, 0.f, 0.f, 0.f};

    for (int k0 = 0; k0 < E_; k0 += 64) {
#pragma unroll
        for (int l = 0; l < 4; ++l) {
            int row = r + (l << 4);
            float4 v = *reinterpret_cast<const float4*>(aptr[l] + k0);
            ushort4 bv;
            bv.x = f2bf(v.x); bv.y = f2bf(v.y); bv.z = f2bf(v.z); bv.w = f2bf(v.w);
            *reinterpret_cast<ushort4*>(&As[row][kq]) = bv;
            *reinterpret_cast<ushort4*>(&Bs[row][kq]) =
                *reinterpret_cast<const ushort4*>(bptr[l] + k0);
        }
        __syncthreads();
#pragma unroll
        for (int ks = 0; ks < 2; ++ks) {
            short8 a = *reinterpret_cast<const short8*>(&As[w * 16 + m][ks * 32 + q * 8]);
#pragma unroll
            for (int nt = 0; nt < 4; ++nt) {
                short8 b = *reinterpret_cast<const short8*>(&Bs[nt * 16 + m][ks * 32 + q * 8]);
                acc[nt] = __builtin_amdgcn_mfma_f32_16x16x32_bf16(a, b, acc[nt], 0, 0, 0);
            }
        }
        __syncthreads();
    }

    // scatter accumulators to LDS: D row = q*4+reg, col = lane&15 (m89-verified)
#pragma unroll
    for (int nt = 0; nt < 4; ++nt)
#pragma unroll
        for (int rr = 0; rr < 4; ++rr)
            Cl[w * 16 + q * 4 + rr][nt * 16 + m] = acc[nt][rr];
    __syncthreads();

    // epilogue: per (row, s2): y2 = sum_c C[row][c]*W2[c,s2] + K2[s2]; out = y2*W3[v]
    for (int task = tid; task < 512; task += 256) {
        int row = task >> 3;
        int s2  = task & 7;
        if (row < rows) {
            float y2 = K2s[s2];
#pragma unroll
            for (int c = 0; c < C_; ++c) y2 += Cl[row][c] * W2s[c * S_ + s2];
            size_t j = (size_t)j_l[row];
            float* o = out + ((size_t)n * TS_ + j * S_ + s2) * OUTW;
#pragma unroll
            for (int v = 0; v < OUTW; ++v) o[v] = y2 * W3s[v];
        }
    }
}

// ---------------------------------------------------------------------------
extern "C" void kernel_launch(void* const* d_in, const int* in_sizes, int n_in,
                              void* d_out, int out_size, void* d_ws, size_t ws_size,
                              hipStream_t stream) {
    const float* x     = (const float*)d_in[0];
    const int*   value = (const int*)d_in[1];
    const int*   depth = (const int*)d_in[2];
    // d_in[3] = pos (unused by reference)
    const float* W1    = (const float*)d_in[4];
    const float* b1    = (const float*)d_in[5];
    const float* W2    = (const float*)d_in[6];
    const float* b2    = (const float*)d_in[7];
    const float* W3    = (const float*)d_in[8];
    float* out = (float*)d_out;

    // workspace layout (~5.3 MB)
    int*   cnt_ns = (int*)d_ws;                       // 64
    int*   sel_tp = cnt_ns + 64;                      // 64*2048
    int*   sel_j  = sel_tp + 64 * 2048;               // 64*2048
    float* K2     = (float*)(sel_j + 64 * 2048);      // 8
    unsigned short* Bb = (unsigned short*)(K2 + 8);   // 4096*512 bf16

    prep_kernel<<<8192, 256, 0, stream>>>(W1, b1, W2, b2, Bb, K2);
    compact_kernel<<<64, 1024, 0, stream>>>(value, depth, cnt_ns, sel_tp, sel_j);
    fill_kernel<<<(OUT_ELEMS + 255) / 256, 256, 0, stream>>>(out, W3, b2);
    dim3 grid(32, 64);
    main_kernel<<<grid, 256, 0, stream>>>(x, Bb, cnt_ns, sel_tp, sel_j, K2, W2, W3, out);
}

// Round 2
// 459.141 us; speedup vs baseline: 1.4645x; 1.4645x over previous
//
#include <hip/hip_runtime.h>

// Problem constants
#define N_    8
#define TP_   2048
#define E_    4096
#define S_    8
#define C_    64
#define T_    16384      // TP_*S_
#define TS_   131072     // T_*S_
#define OUTW  17         // V+1
#define OUT_ELEMS 17825792  // N_*TS_*OUTW
#define F4_PER_N 557056     // 16384 rows * 34 float4 per row
#define F4_TOTAL 4456448    // OUT_ELEMS/4

typedef __attribute__((ext_vector_type(8))) short short8;
typedef __attribute__((ext_vector_type(4))) float float4v;

static __device__ __forceinline__ unsigned short f2bf(float f) {
    unsigned int u = __builtin_bit_cast(unsigned int, f);
    u += 0x7FFFu + ((u >> 16) & 1u);   // round-to-nearest-even
    return (unsigned short)(u >> 16);
}

// ---------------------------------------------------------------------------
// prep: LDS-tiled transpose W1 [4096][512] fp32 -> Bb [512][4096] bf16
//   Bb row index = c*8+s (natural W1 inner order); main indexes rows as c*8+s.
//   Block (0,0) also computes K2[s2] = b2 + sum_c b1[c]*W2[c,0,s2].
// ---------------------------------------------------------------------------
__global__ __launch_bounds__(256) void prep_kernel(
    const float* __restrict__ W1, const float* __restrict__ b1,
    const float* __restrict__ W2, const float* __restrict__ b2,
    unsigned short* __restrict__ Bb, float* __restrict__ K2)
{
    __shared__ float tile[64][65];
    const int tid = threadIdx.x;
    if (blockIdx.x == 0 && blockIdx.y == 0 && tid < 8) {
        int s2 = tid;
        float acc = b2[0];
        for (int c = 0; c < C_; ++c) acc += b1[c] * W2[c * S_ + s2];
        K2[s2] = acc;
    }
    const int e0  = blockIdx.x * 64;   // 64 e-tiles
    const int cs0 = blockIdx.y * 64;   // 8 cs-tiles
    // load 64x64 fp32 tile, coalesced along cs
    {
        int rr = tid >> 2;        // e row 0..63
        int c4 = tid & 3;
        for (int i = 0; i < 4; ++i) {
            int f4 = c4 + i * 4;  // 0..15
            float4 v = *(const float4*)&W1[(size_t)(e0 + rr) * 512 + cs0 + f4 * 4];
            tile[f4 * 4 + 0][rr] = v.x;
            tile[f4 * 4 + 1][rr] = v.y;
            tile[f4 * 4 + 2][rr] = v.z;
            tile[f4 * 4 + 3][rr] = v.w;
        }
    }
    __syncthreads();
    // store transposed bf16, coalesced along e
    {
        int cs  = tid >> 2;       // 0..63
        int seg = tid & 3;        // 16 shorts each
        for (int h = 0; h < 2; ++h) {
            short8 o;
#pragma unroll
            for (int j = 0; j < 8; ++j)
                o[j] = (short)f2bf(tile[cs][seg * 16 + h * 8 + j]);
            *(short8*)&Bb[(size_t)(cs0 + cs) * E_ + e0 + seg * 16 + h * 8] = o;
        }
    }
}

// ---------------------------------------------------------------------------
// compact: per (n,s) block; wave-shuffle scan; parallel 64-ary argmax search;
// builds per-group gathered row lists + global tile work-list.
// ---------------------------------------------------------------------------
__global__ __launch_bounds__(256) void compact_kernel(
    const int* __restrict__ value, const int* __restrict__ depth,
    int* __restrict__ cnt_ns, int* __restrict__ cnt_total,
    int* __restrict__ tile_counter, int* __restrict__ tiles,
    int* __restrict__ sel_tp, int* __restrict__ sel_j)
{
    const int g = blockIdx.x;          // n*8 + s
    const int n = g >> 3;
    const int s = g & 7;
    const int tid  = threadIdx.x;
    const int lane = tid & 63;
    const int wv   = tid >> 6;

    __shared__ int idx_sh;
    __shared__ unsigned int wsum[4];

    const int* d = depth + (size_t)n * T_;
    if (tid < 64) {                    // wave 0: 64-ary search, 3 rounds
        int maxv = d[T_ - 1];
        int lower = 0, upper = T_ - 1;
        for (int rnd = 0; rnd < 3; ++rnd) {
            int span = upper - lower;
            int step = (span + 63) >> 6;
            if (step < 1) step = 1;
            int p = lower + lane * step;
            if (p > upper) p = upper;
            unsigned long long b = __ballot(d[p] == maxv);
            int f = __ffsll((long long)b) - 1;   // ballot never 0: d[upper]==maxv
            int nu = lower + f * step; if (nu > upper) nu = upper;
            int nl = (f == 0) ? lower : lower + (f - 1) * step + 1;
            if (nl > nu) nl = nu;
            lower = nl; upper = nu;
        }
        if (lane == 0) idx_sh = lower;
    }
    __syncthreads();
    const int idx = idx_sh;
    const int* val = value + (size_t)n * T_;

    const int t0 = tid * 64;
    unsigned int packed = 0;   // (any-count << 16) | s-residue count
    for (int i = 0; i < 64; ++i) {
        int t = t0 + i;
        if (t < idx && val[t] == 2) {
            packed += 0x10000u;
            if ((t & 7) == s) packed += 1u;
        }
    }
    // wave inclusive scan
    unsigned int inc = packed;
#pragma unroll
    for (int off = 1; off < 64; off <<= 1) {
        unsigned int u = __shfl_up((int)inc, off, 64);
        if (lane >= off) inc += u;
    }
    if (lane == 63) wsum[wv] = inc;
    __syncthreads();
    unsigned int woff = 0;
    for (int ww = 0; ww < wv; ++ww) woff += wsum[ww];
    unsigned int excl = woff + inc - packed;
    int any_rank = (int)(excl >> 16);
    int s_rank   = (int)(excl & 0xFFFFu);
    for (int i = 0; i < 64; ++i) {
        int t = t0 + i;
        if (t < idx && val[t] == 2) {
            if ((t & 7) == s) {
                sel_tp[g * 2048 + s_rank] = t >> 3;
                sel_j [g * 2048 + s_rank] = any_rank;
                ++s_rank;
            }
            ++any_rank;
        }
    }
    if (tid == 255) {
        unsigned int tot = woff + inc;
        int cnt = (int)(tot & 0xFFFFu);
        cnt_ns[g] = cnt;
        if (s == 0) cnt_total[n] = (int)(tot >> 16);
        int ntl = (cnt + 63) >> 6;
        int base = atomicAdd(tile_counter, ntl);
        for (int i = 0; i < ntl; ++i) tiles[base + i] = (g << 8) | i;
    }
}

// ---------------------------------------------------------------------------
// fill: vectorized b2*W3 pattern; skips rows j < cnt_total[n] (main overwrites)
// ---------------------------------------------------------------------------
__global__ __launch_bounds__(256) void fill_kernel(
    float* __restrict__ out, const float* __restrict__ W3,
    const float* __restrict__ b2, const int* __restrict__ cnt_total)
{
    __shared__ float pat[136];
    const int tid = threadIdx.x;
    if (tid < 136) pat[tid] = b2[0] * W3[tid % OUTW];
    __syncthreads();
    int i4 = blockIdx.x * 256 + tid;          // < F4_TOTAL exactly
    int n   = i4 / F4_PER_N;
    int rem = i4 - n * F4_PER_N;
    int j   = rem / 34;                       // output row within sample (136 floats = 34 f4)
    if (j >= cnt_total[n]) {
        int o = (rem - j * 34) * 4;
        float4 v = { pat[o], pat[o + 1], pat[o + 2], pat[o + 3] };
        *(float4*)&out[(size_t)i4 * 4] = v;
    }
}

// ---------------------------------------------------------------------------
// main: work-list driven gathered bf16 MFMA GEMM (64 rows x 64 ch, K=4096),
// register-double-buffered staging (1 barrier/iter), fused conv2/linear.
// ---------------------------------------------------------------------------
__global__ __launch_bounds__(256) void main_kernel(
    const float* __restrict__ x, const unsigned short* __restrict__ Bb,
    const int* __restrict__ tile_counter, const int* __restrict__ tiles,
    const int* __restrict__ cnt_ns, const int* __restrict__ sel_tp,
    const int* __restrict__ sel_j, const float* __restrict__ K2,
    const float* __restrict__ W2, const float* __restrict__ W3,
    float* __restrict__ out)
{
    __shared__ __align__(16) char arena[36864];  // bufA[2]+bufB[2] (9216 each) ∪ Cl
    unsigned short (*bufA)[64][72] = (unsigned short (*)[64][72])arena;
    unsigned short (*bufB)[64][72] = (unsigned short (*)[64][72])(arena + 18432);
    float (*Cl)[68] = (float (*)[68])arena;       // 64x68 fp32 = 17408 B, aliased
    __shared__ int tp_l[64], j_l[64];
    __shared__ float W2s[C_ * S_];
    __shared__ float W3s[OUTW];
    __shared__ float K2s[S_];

    const int tid = threadIdx.x;
    for (int i = tid; i < C_ * S_; i += 256) W2s[i] = W2[i];
    if (tid < OUTW) W3s[tid] = W3[tid];
    if (tid < S_)   K2s[tid] = K2[tid];

    const int ntile = *tile_counter;

    const int lane = tid & 63;
    const int w    = tid >> 6;        // wave id: A rows [w*16, w*16+16)
    const int m    = lane & 15;
    const int q    = lane >> 4;
    const int r    = tid >> 4;        // staging row 0..15
    const int kq   = (tid & 15) << 2; // staging k-offset 0..60

    for (int ti = blockIdx.x; ti < ntile; ti += gridDim.x) {
        const int ent = tiles[ti];
        const int g = ent >> 8;
        const int n = g >> 3;
        const int s = g & 7;
        const int m0 = (ent & 255) * 64;
        const int rows = min(64, cnt_ns[g] - m0);

        __syncthreads();   // previous tile's epilogue fully done (Cl/tp_l reuse)
        if (tid < 64) {
            int tp = 0, j = 0;
            if (tid < rows) {
                tp = sel_tp[g * 2048 + m0 + tid];
                j  = sel_j [g * 2048 + m0 + tid];
            }
            tp_l[tid] = tp;
            j_l[tid]  = j;
        }
        __syncthreads();

        const float* ap[4];
        const unsigned short* bp[4];
#pragma unroll
        for (int l = 0; l < 4; ++l) {
            int row = r + (l << 4);
            ap[l] = x + ((size_t)n * TP_ + tp_l[row]) * E_ + kq;
            bp[l] = Bb + ((size_t)(row * 8 + s)) * E_ + kq;   // Bb row = c*8+s
        }

        // prefetch tile 0 into registers
        float4  Af[4];
        ushort4 Bf[4];
#pragma unroll
        for (int l = 0; l < 4; ++l) {
            Af[l] = *(const float4*)(ap[l]);
            Bf[l] = *(const ushort4*)(bp[l]);
        }

        float4v acc[4];
#pragma unroll
        for (int nt = 0; nt < 4; ++nt) acc[nt] = (float4v){0.f, 0.f, 0.f, 0.f};

        for (int kb = 0; kb < 64; ++kb) {
            const int p = kb & 1;
#pragma unroll
            for (int l = 0; l < 4; ++l) {
                int row = r + (l << 4);
                ushort4 av;
                av.x = f2bf(Af[l].x); av.y = f2bf(Af[l].y);
                av.z = f2bf(Af[l].z); av.w = f2bf(Af[l].w);
                *(ushort4*)&bufA[p][row][kq] = av;
                *(ushort4*)&bufB[p][row][kq] = Bf[l];
            }
            __syncthreads();
            if (kb < 63) {            // prefetch next k-chunk during compute
                const int k0 = (kb + 1) * 64;
#pragma unroll
                for (int l = 0; l < 4; ++l) {
                    Af[l] = *(const float4*)(ap[l] + k0);
                    Bf[l] = *(const ushort4*)(bp[l] + k0);
                }
            }
#pragma unroll
            for (int ks = 0; ks < 2; ++ks) {
                short8 a = *(const short8*)&bufA[p][w * 16 + m][ks * 32 + q * 8];
#pragma unroll
                for (int nt = 0; nt < 4; ++nt) {
                    short8 b = *(const short8*)&bufB[p][nt * 16 + m][ks * 32 + q * 8];
                    acc[nt] = __builtin_amdgcn_mfma_f32_16x16x32_bf16(a, b, acc[nt], 0, 0, 0);
                }
            }
        }
        __syncthreads();   // all LDS reads done before Cl alias write

        // D layout: row = q*4+reg, col = lane&15 (m89-verified)
#pragma unroll
        for (int nt = 0; nt < 4; ++nt)
#pragma unroll
            for (int rr = 0; rr < 4; ++rr)
                Cl[w * 16 + q * 4 + rr][nt * 16 + m] = acc[nt][rr];
        __syncthreads();

        // epilogue: y2 = K2[s2] + sum_c C[row][c]*W2[c,s2]; out row = y2*W3
        for (int task = tid; task < 512; task += 256) {
            int row = task >> 3;
            int s2  = task & 7;
            if (row < rows) {
                float y2 = K2s[s2];
#pragma unroll
                for (int c = 0; c < C_; ++c) y2 += Cl[row][c] * W2s[c * S_ + s2];
                float* o = out + ((size_t)n * TS_ + (size_t)j_l[row] * S_ + s2) * OUTW;
#pragma unroll
                for (int v = 0; v < OUTW; ++v) o[v] = y2 * W3s[v];
            }
        }
    }
}

// ---------------------------------------------------------------------------
extern "C" void kernel_launch(void* const* d_in, const int* in_sizes, int n_in,
                              void* d_out, int out_size, void* d_ws, size_t ws_size,
                              hipStream_t stream) {
    const float* x     = (const float*)d_in[0];
    const int*   value = (const int*)d_in[1];
    const int*   depth = (const int*)d_in[2];
    // d_in[3] = pos (unused by reference)
    const float* W1    = (const float*)d_in[4];
    const float* b1    = (const float*)d_in[5];
    const float* W2    = (const float*)d_in[6];
    const float* b2    = (const float*)d_in[7];
    const float* W3    = (const float*)d_in[8];
    float* out = (float*)d_out;

    // workspace layout (~5.25 MB)
    unsigned short* Bb = (unsigned short*)d_ws;            // 512*4096 bf16 = 4 MB
    float* K2          = (float*)(Bb + 512 * 4096);        // 8
    int* tile_counter  = (int*)(K2 + 8);                   // 1
    int* cnt_ns        = tile_counter + 1;                 // 64
    int* cnt_total     = cnt_ns + 64;                      // 8
    int* tiles         = cnt_total + 8;                    // 2048 max
    int* sel_tp        = tiles + 2048;                     // 64*2048
    int* sel_j         = sel_tp + 64 * 2048;               // 64*2048

    hipMemsetAsync(tile_counter, 0, sizeof(int), stream);

    dim3 pgrid(64, 8);
    prep_kernel<<<pgrid, 256, 0, stream>>>(W1, b1, W2, b2, Bb, K2);
    compact_kernel<<<64, 256, 0, stream>>>(value, depth, cnt_ns, cnt_total,
                                           tile_counter, tiles, sel_tp, sel_j);
    fill_kernel<<<F4_TOTAL / 256, 256, 0, stream>>>(out, W3, b2, cnt_total);
    main_kernel<<<1024, 256, 0, stream>>>(x, Bb, tile_counter, tiles, cnt_ns,
                                          sel_tp, sel_j, K2, W2, W3, out);
}